// Round 2
// baseline (572.066 us; speedup 1.0000x reference)
//
#include <hip/hip_runtime.h>

typedef unsigned short ushort_t;
typedef __attribute__((ext_vector_type(8))) short short8;
typedef __attribute__((ext_vector_type(4))) float f32x4;
typedef __attribute__((ext_vector_type(4))) int int4v;

#define RNUM 8
#define FDIM 128

__device__ __forceinline__ float bf2f(ushort_t u) {
    union { unsigned int i; float f; } x;
    x.i = ((unsigned int)u) << 16;
    return x.f;
}
__device__ __forceinline__ ushort_t f2bf(float f) {
    union { float f; unsigned int i; } x;
    x.f = f;
    unsigned int u = x.i;
    u += 0x7fffu + ((u >> 16) & 1u);   // round-to-nearest-even
    return (ushort_t)(u >> 16);
}

// ---------------- f32 -> bf16 cast ----------------

__global__ void cast_f32_bf16(const float* __restrict__ in, ushort_t* __restrict__ out, int n) {
    int i = (blockIdx.x * 256 + threadIdx.x) * 4;
    if (i + 3 < n) {
        float4 v = *(const float4*)(in + i);
        ushort_t o[4] = {f2bf(v.x), f2bf(v.y), f2bf(v.z), f2bf(v.w)};
        *(int2*)(out + i) = *(int2*)o;
    } else {
        for (int k = 0; k < 4 && i + k < n; ++k) out[i + k] = f2bf(in[i + k]);
    }
}

// ---------------- CSR build ----------------

__global__ void zero_kernel(int* p, int n) {
    int i = blockIdx.x * 256 + threadIdx.x;
    if (i < n) p[i] = 0;
}

__global__ void hist_kernel(const int* __restrict__ dst, const int* __restrict__ et,
                            int* cnt, int E) {
    int i = blockIdx.x * 256 + threadIdx.x;
    if (i < E) atomicAdd(&cnt[dst[i] * RNUM + et[i]], 1);
}

// per-block exclusive scan of 1024-element chunks; block sums out
__global__ __launch_bounds__(256) void scan_a(const int* __restrict__ cnt,
                                              int* __restrict__ part,
                                              int* __restrict__ bsum, int n) {
    __shared__ int sd[256];
    int tid = threadIdx.x;
    int base = blockIdx.x * 1024 + tid * 4;
    int v0 = (base + 0 < n) ? cnt[base + 0] : 0;
    int v1 = (base + 1 < n) ? cnt[base + 1] : 0;
    int v2 = (base + 2 < n) ? cnt[base + 2] : 0;
    int v3 = (base + 3 < n) ? cnt[base + 3] : 0;
    int tot = v0 + v1 + v2 + v3;
    sd[tid] = tot;
    __syncthreads();
    for (int off = 1; off < 256; off <<= 1) {
        int t = (tid >= off) ? sd[tid - off] : 0;
        __syncthreads();
        sd[tid] += t;
        __syncthreads();
    }
    int run = sd[tid] - tot;  // exclusive prefix for this thread
    if (base + 0 < n) part[base + 0] = run; run += v0;
    if (base + 1 < n) part[base + 1] = run; run += v1;
    if (base + 2 < n) part[base + 2] = run; run += v2;
    if (base + 3 < n) part[base + 3] = run;
    if (tid == 255) bsum[blockIdx.x] = sd[255];
}

__global__ __launch_bounds__(512) void scan_b(int* bsum, int nb) {
    __shared__ int sd[512];
    int tid = threadIdx.x;
    int v = (tid < nb) ? bsum[tid] : 0;
    sd[tid] = v;
    __syncthreads();
    for (int off = 1; off < 512; off <<= 1) {
        int t = (tid >= off) ? sd[tid - off] : 0;
        __syncthreads();
        sd[tid] += t;
        __syncthreads();
    }
    if (tid < nb) bsum[tid] = sd[tid] - v;  // exclusive block offsets
}

__global__ void scan_c(int* row_ptr, int* cursor, const int* __restrict__ bsum,
                       int n, int total) {
    int i = blockIdx.x * 256 + threadIdx.x;
    if (i < n) {
        int v = row_ptr[i] + bsum[i >> 10];
        row_ptr[i] = v;
        cursor[i] = v;
    }
    if (i == 0) row_ptr[n] = total;
}

__global__ void scatter_kernel(const int* __restrict__ src, const int* __restrict__ dst,
                               const int* __restrict__ et, int* cursor,
                               int* __restrict__ ssrc, int E) {
    int i = blockIdx.x * 256 + threadIdx.x;
    if (i < E) {
        int seg = dst[i] * RNUM + et[i];
        int pos = atomicAdd(&cursor[seg], 1);
        ssrc[pos] = src[i];
    }
}

// ------- weight transpose + bf16 cast: Wt[r][h][f] = bf16(W[r][f][h]), r=8 -> root -------

__global__ __launch_bounds__(256) void transpose_w(const float* __restrict__ rel_w,
                                                   const float* __restrict__ root_w,
                                                   ushort_t* __restrict__ Wt) {
    int r = blockIdx.x;  // 0..8
    const float* src = (r < 8) ? (rel_w + r * 16384) : root_w;
    __shared__ ushort_t t[128 * 130];
    for (int idx = threadIdx.x; idx < 16384; idx += 256)
        t[(idx >> 7) * 130 + (idx & 127)] = f2bf(src[idx]);
    __syncthreads();
    ushort_t* d = Wt + r * 16384;
    for (int idx = threadIdx.x; idx < 16384; idx += 256)
        d[idx] = t[(idx & 127) * 130 + (idx >> 7)];
}

// ---------------- fused RGCN conv layer ----------------
// 64 nodes per block. For r in 0..8 (8 = root): build mean tile in LDS, MFMA vs Wt[r].
// X is bf16 [N,128]. Output: bf16 (inter-layer) or f32 (final), per OUT_BF16.

template <bool OUT_BF16>
__global__ __launch_bounds__(256) void rgcn_conv(
    const ushort_t* __restrict__ X, const int* __restrict__ row_ptr,
    const int* __restrict__ ssrc, const ushort_t* __restrict__ Wt,
    const float* __restrict__ bias, void* __restrict__ out,
    int N, int do_relu) {
    __shared__ ushort_t Atile[64 * 136];   // rows padded to 272B
    __shared__ ushort_t Btile[128 * 136];
    __shared__ float biasS[128];
    int tid = threadIdx.x;
    int wid = tid >> 6, lane = tid & 63;
    int l16 = lane & 15, q = lane >> 4;
    int nodeBase = blockIdx.x * 64;
    if (tid < 128) biasS[tid] = bias[tid];

    f32x4 cacc[8];
#pragma unroll
    for (int t = 0; t < 8; ++t) cacc[t] = (f32x4){0.f, 0.f, 0.f, 0.f};

    for (int r = 0; r < 9; ++r) {
        __syncthreads();  // previous iteration's MFMA reads done
        // stage B = Wt[r] (W^T, [h][f]) into LDS with 272B row pitch
        const int4v* wsrc = (const int4v*)(Wt + r * 16384);
#pragma unroll
        for (int i = 0; i < 8; ++i) {
            int idx = i * 256 + tid;  // 0..2047, 16B each
            int4v v = wsrc[idx];
            *(int4v*)&Btile[(idx >> 4) * 136 + (idx & 15) * 8] = v;
        }
        // build A = mean tile; 4 waves x 16 nodes, 4 nodes in flight per wave
#pragma unroll
        for (int g = 0; g < 4; ++g) {
            int nl = wid * 16 + g * 4 + q;
            int node = nodeBase + nl;
            if (node < N) {
                if (r == 8) {
                    int4v v = ((const int4v*)(X + (size_t)node * FDIM))[l16];
                    *(int4v*)&Atile[nl * 136 + l16 * 8] = v;
                } else {
                    float acc[8];
#pragma unroll
                    for (int k = 0; k < 8; ++k) acc[k] = 0.f;
                    int seg = node * RNUM + r;
                    int s0 = row_ptr[seg], s1 = row_ptr[seg + 1];
                    for (int e = s0; e < s1; ++e) {
                        int sidx = ssrc[e];
                        int4v v = ((const int4v*)(X + (size_t)sidx * FDIM))[l16];
                        ushort_t* pv = (ushort_t*)&v;
#pragma unroll
                        for (int k = 0; k < 8; ++k) acc[k] += bf2f(pv[k]);
                    }
                    float sc = (s1 > s0) ? 1.0f / (float)(s1 - s0) : 0.f;
                    ushort_t ov[8];
#pragma unroll
                    for (int k = 0; k < 8; ++k) ov[k] = f2bf(acc[k] * sc);
                    *(int4v*)&Atile[nl * 136 + l16 * 8] = *(int4v*)ov;
                }
            }
        }
        __syncthreads();
        // MFMA: wave wid owns A rows [wid*16, wid*16+16), all 8 h-tiles
#pragma unroll
        for (int s = 0; s < 4; ++s) {
            short8 a = *(const short8*)&Atile[(wid * 16 + l16) * 136 + s * 32 + q * 8];
#pragma unroll
            for (int t = 0; t < 8; ++t) {
                short8 b = *(const short8*)&Btile[(t * 16 + l16) * 136 + s * 32 + q * 8];
                cacc[t] = __builtin_amdgcn_mfma_f32_16x16x32_bf16(a, b, cacc[t], 0, 0, 0);
            }
        }
    }
    // epilogue: C layout col=lane&15, row=quad*4+reg
#pragma unroll
    for (int t = 0; t < 8; ++t) {
        int h = t * 16 + l16;
        float bv = biasS[h];
#pragma unroll
        for (int reg = 0; reg < 4; ++reg) {
            int node = nodeBase + wid * 16 + q * 4 + reg;
            if (node < N) {
                float v = cacc[t][reg] + bv;
                if (do_relu) v = fmaxf(v, 0.f);
                if (OUT_BF16)
                    ((ushort_t*)out)[(size_t)node * FDIM + h] = f2bf(v);
                else
                    ((float*)out)[(size_t)node * FDIM + h] = v;
            }
        }
    }
}

__global__ void copy_emb(const float* __restrict__ e, float* __restrict__ out, int n) {
    int i = blockIdx.x * 256 + threadIdx.x;
    if (i < n) out[i] = e[i];
}

// ---------------- launch ----------------

extern "C" void kernel_launch(void* const* d_in, const int* in_sizes, int n_in,
                              void* d_out, int out_size, void* d_ws, size_t ws_size,
                              hipStream_t stream) {
    const float* x        = (const float*)d_in[0];
    const int* edge_index = (const int*)d_in[1];
    const int* edge_type  = (const int*)d_in[2];
    const float* rel_w0   = (const float*)d_in[3];
    const float* root_w0  = (const float*)d_in[4];
    const float* bias0    = (const float*)d_in[5];
    const float* rel_w1   = (const float*)d_in[6];
    const float* root_w1  = (const float*)d_in[7];
    const float* bias1    = (const float*)d_in[8];
    const float* rel_emb  = (const float*)d_in[9];

    int N = in_sizes[0] / FDIM;   // 50000
    int E = in_sizes[1] / 2;      // 800000
    int NSEG = N * RNUM;          // 400000
    const int* src = edge_index;
    const int* dst = edge_index + E;

    char* w = (char*)d_ws;
    auto alloc = [&](size_t bytes) -> char* {
        char* p = w;
        w += (bytes + 255) & ~(size_t)255;
        return p;
    };
    int* cnt       = (int*)alloc((size_t)NSEG * 4);      // reused as cursor after scan_a
    int* row_ptr   = (int*)alloc((size_t)(NSEG + 1) * 4);
    int* bsum      = (int*)alloc(1024 * 4);
    int* ssrc      = (int*)alloc((size_t)E * 4);
    ushort_t* Wt   = (ushort_t*)alloc((size_t)2 * 9 * 16384 * 2);
    ushort_t* Xbf  = (ushort_t*)alloc((size_t)N * FDIM * 2);
    ushort_t* hbuf = (ushort_t*)alloc((size_t)N * FDIM * 2);
    int* cursor = cnt;  // cnt dead after scan_a
    (void)ws_size; (void)n_in; (void)out_size;

    int nb_seg  = (NSEG + 255) / 256;
    int nb_E    = (E + 255) / 256;
    int nb_scan = (NSEG + 1023) / 1024;  // 391 <= 512
    int nb_conv = (N + 63) / 64;
    int nb_cast = (N * FDIM + 1023) / 1024;

    zero_kernel<<<nb_seg, 256, 0, stream>>>(cnt, NSEG);
    hist_kernel<<<nb_E, 256, 0, stream>>>(dst, edge_type, cnt, E);
    scan_a<<<nb_scan, 256, 0, stream>>>(cnt, row_ptr, bsum, NSEG);
    scan_b<<<1, 512, 0, stream>>>(bsum, nb_scan);
    scan_c<<<nb_seg, 256, 0, stream>>>(row_ptr, cursor, bsum, NSEG, E);
    scatter_kernel<<<nb_E, 256, 0, stream>>>(src, dst, edge_type, cursor, ssrc, E);
    transpose_w<<<9, 256, 0, stream>>>(rel_w0, root_w0, Wt);
    transpose_w<<<9, 256, 0, stream>>>(rel_w1, root_w1, Wt + 9 * 16384);
    cast_f32_bf16<<<nb_cast, 256, 0, stream>>>(x, Xbf, N * FDIM);

    rgcn_conv<true><<<nb_conv, 256, 0, stream>>>(Xbf, row_ptr, ssrc, Wt, bias0,
                                                 (void*)hbuf, N, 1);
    rgcn_conv<false><<<nb_conv, 256, 0, stream>>>(hbuf, row_ptr, ssrc, Wt + 9 * 16384, bias1,
                                                  d_out, N, 0);
    copy_emb<<<4, 256, 0, stream>>>(rel_emb, (float*)d_out + (size_t)N * FDIM,
                                    in_sizes[9]);
}

// Round 3
// 349.695 us; speedup vs baseline: 1.6359x; 1.6359x over previous
//
#include <hip/hip_runtime.h>

typedef unsigned short ushort_t;
typedef __attribute__((ext_vector_type(8))) short short8;
typedef __attribute__((ext_vector_type(4))) float f32x4;
typedef __attribute__((ext_vector_type(4))) int int4v;

#define RNUM 8
#define FDIM 128
#define KDIM 1152   // 9 * 128: slots 0..7 = per-relation means, slot 8 = x / relu(h)

__device__ __forceinline__ float bf2f(ushort_t u) {
    union { unsigned int i; float f; } x;
    x.i = ((unsigned int)u) << 16;
    return x.f;
}
__device__ __forceinline__ ushort_t f2bf(float f) {
    union { float f; unsigned int i; } x;
    x.f = f;
    unsigned int u = x.i;
    u += 0x7fffu + ((u >> 16) & 1u);   // round-to-nearest-even
    return (ushort_t)(u >> 16);
}

// async global->LDS, 16B per lane; LDS side must be wave-contiguous
__device__ __forceinline__ void gl_lds16(const void* g, void* s) {
    __builtin_amdgcn_global_load_lds(
        (const __attribute__((address_space(1))) unsigned int*)g,
        (__attribute__((address_space(3))) unsigned int*)s, 16, 0, 0);
}

// ---------------- CSR build ----------------

__global__ void zero_kernel(int* p, int n) {
    int i = blockIdx.x * 256 + threadIdx.x;
    if (i < n) p[i] = 0;
}

__global__ void hist_kernel(const int* __restrict__ dst, const int* __restrict__ et,
                            int* cnt, int E) {
    int i = blockIdx.x * 256 + threadIdx.x;
    if (i < E) atomicAdd(&cnt[dst[i] * RNUM + et[i]], 1);
}

__global__ __launch_bounds__(256) void scan_a(const int* __restrict__ cnt,
                                              int* __restrict__ part,
                                              int* __restrict__ bsum, int n) {
    __shared__ int sd[256];
    int tid = threadIdx.x;
    int base = blockIdx.x * 1024 + tid * 4;
    int v0 = (base + 0 < n) ? cnt[base + 0] : 0;
    int v1 = (base + 1 < n) ? cnt[base + 1] : 0;
    int v2 = (base + 2 < n) ? cnt[base + 2] : 0;
    int v3 = (base + 3 < n) ? cnt[base + 3] : 0;
    int tot = v0 + v1 + v2 + v3;
    sd[tid] = tot;
    __syncthreads();
    for (int off = 1; off < 256; off <<= 1) {
        int t = (tid >= off) ? sd[tid - off] : 0;
        __syncthreads();
        sd[tid] += t;
        __syncthreads();
    }
    int run = sd[tid] - tot;
    if (base + 0 < n) part[base + 0] = run; run += v0;
    if (base + 1 < n) part[base + 1] = run; run += v1;
    if (base + 2 < n) part[base + 2] = run; run += v2;
    if (base + 3 < n) part[base + 3] = run;
    if (tid == 255) bsum[blockIdx.x] = sd[255];
}

__global__ __launch_bounds__(512) void scan_b(int* bsum, int nb) {
    __shared__ int sd[512];
    int tid = threadIdx.x;
    int v = (tid < nb) ? bsum[tid] : 0;
    sd[tid] = v;
    __syncthreads();
    for (int off = 1; off < 512; off <<= 1) {
        int t = (tid >= off) ? sd[tid - off] : 0;
        __syncthreads();
        sd[tid] += t;
        __syncthreads();
    }
    if (tid < nb) bsum[tid] = sd[tid] - v;
}

__global__ void scan_c(int* row_ptr, int* cursor, const int* __restrict__ bsum,
                       int n, int total) {
    int i = blockIdx.x * 256 + threadIdx.x;
    if (i < n) {
        int v = row_ptr[i] + bsum[i >> 10];
        row_ptr[i] = v;
        cursor[i] = v;
    }
    if (i == 0) row_ptr[n] = total;
}

__global__ void scatter_kernel(const int* __restrict__ src, const int* __restrict__ dst,
                               const int* __restrict__ et, int* cursor,
                               int* __restrict__ ssrc, int E) {
    int i = blockIdx.x * 256 + threadIdx.x;
    if (i < E) {
        int seg = dst[i] * RNUM + et[i];
        int pos = atomicAdd(&cursor[seg], 1);
        ssrc[pos] = src[i];
    }
}

// ------- weight transpose + bf16 cast: Wt[r][h][f] = bf16(W[r][f][h]), r=8 -> root -------

__global__ __launch_bounds__(256) void transpose_w(const float* __restrict__ rel_w,
                                                   const float* __restrict__ root_w,
                                                   ushort_t* __restrict__ Wt) {
    int r = blockIdx.x;  // 0..8
    const float* src = (r < 8) ? (rel_w + r * 16384) : root_w;
    __shared__ ushort_t t[128 * 130];
    for (int idx = threadIdx.x; idx < 16384; idx += 256)
        t[(idx >> 7) * 130 + (idx & 127)] = f2bf(src[idx]);
    __syncthreads();
    ushort_t* d = Wt + r * 16384;
    for (int idx = threadIdx.x; idx < 16384; idx += 256)
        d[idx] = t[(idx & 127) * 130 + (idx >> 7)];
}

// ---------------- cast x (f32) into Mx slot 8 ----------------

__global__ void cast_x(const float* __restrict__ x, ushort_t* __restrict__ Mx, int total) {
    int i = (blockIdx.x * 256 + threadIdx.x) * 8;
    if (i >= total) return;
    float4 v0 = *(const float4*)(x + i);
    float4 v1 = *(const float4*)(x + i + 4);
    ushort_t o[8] = {f2bf(v0.x), f2bf(v0.y), f2bf(v0.z), f2bf(v0.w),
                     f2bf(v1.x), f2bf(v1.y), f2bf(v1.z), f2bf(v1.w)};
    int row = i >> 7, col = i & 127;
    *(int4v*)(Mx + (size_t)row * KDIM + 1024 + col) = *(int4v*)o;
}

// ---------------- phase A: per-(node,rel) segment means ----------------
// one quarter-wave (16 lanes x 16B) per segment; gather rows from Mx slot 8;
// write mean into Mx slot (seg&7). 16 segs/block, zero LDS -> max occupancy.

__global__ __launch_bounds__(256) void seg_mean(const int* __restrict__ row_ptr,
                                                const int* __restrict__ ssrc,
                                                ushort_t* Mx, int NSEG) {
    int t = blockIdx.x * 256 + threadIdx.x;
    int seg = t >> 4;
    int l16 = t & 15;
    if (seg >= NSEG) return;
    int s0 = row_ptr[seg], s1 = row_ptr[seg + 1];
    float acc0[8], acc1[8];
#pragma unroll
    for (int k = 0; k < 8; ++k) { acc0[k] = 0.f; acc1[k] = 0.f; }
    const ushort_t* gbase = Mx + 1024 + (size_t)l16 * 8;
    int e = s0;
    for (; e + 1 < s1; e += 2) {
        int j0 = ssrc[e], j1 = ssrc[e + 1];
        int4v v0 = *(const int4v*)(gbase + (size_t)j0 * KDIM);
        int4v v1 = *(const int4v*)(gbase + (size_t)j1 * KDIM);
        ushort_t* p0 = (ushort_t*)&v0;
        ushort_t* p1 = (ushort_t*)&v1;
#pragma unroll
        for (int k = 0; k < 8; ++k) { acc0[k] += bf2f(p0[k]); acc1[k] += bf2f(p1[k]); }
    }
    if (e < s1) {
        int j0 = ssrc[e];
        int4v v0 = *(const int4v*)(gbase + (size_t)j0 * KDIM);
        ushort_t* p0 = (ushort_t*)&v0;
#pragma unroll
        for (int k = 0; k < 8; ++k) acc0[k] += bf2f(p0[k]);
    }
    float sc = (s1 > s0) ? 1.0f / (float)(s1 - s0) : 0.f;
    ushort_t ov[8];
#pragma unroll
    for (int k = 0; k < 8; ++k) ov[k] = f2bf((acc0[k] + acc1[k]) * sc);
    *(int4v*)(Mx + (size_t)(seg >> 3) * KDIM + (seg & 7) * 128 + l16 * 8) = *(int4v*)ov;
}

// ---------------- phase B: dense GEMM  C[128n x 128h] = Mx[128n x 1152k] @ Wt^T ----------
// A,B staged per r-slot via global_load_lds (16B) into XOR-swizzled contiguous LDS.
// LDS chunk layout: 16B chunk c of row n stored at position c ^ (n & 15).

template <bool FINAL>
__global__ __launch_bounds__(256) void rgcn_gemm(
    const ushort_t* Mx, const ushort_t* __restrict__ Wt,
    const float* __restrict__ bias, float* __restrict__ outF,
    ushort_t* MxOut, int N) {
    __shared__ ushort_t As[128 * 128];
    __shared__ ushort_t Bs[128 * 128];
    int tid = threadIdx.x;
    int wid = tid >> 6, lane = tid & 63;
    int l16 = lane & 15, q = lane >> 4;
    int nodeBase = blockIdx.x * 128;

    f32x4 acc[2][8];
#pragma unroll
    for (int rt = 0; rt < 2; ++rt)
#pragma unroll
        for (int ct = 0; ct < 8; ++ct) acc[rt][ct] = (f32x4){0.f, 0.f, 0.f, 0.f};

    for (int r = 0; r < 9; ++r) {
        __syncthreads();  // previous iteration's LDS reads done
#pragma unroll
        for (int i = 0; i < 8; ++i) {
            int L = i * 256 + tid;          // 16B slot index, wave-contiguous
            int row = L >> 4;               // 0..127
            int c = (L & 15) ^ (row & 15);  // logical chunk for this slot
            gl_lds16(Mx + (size_t)(nodeBase + row) * KDIM + r * 128 + c * 8,
                     (char*)As + (size_t)L * 16);
            gl_lds16(Wt + r * 16384 + row * 128 + c * 8,
                     (char*)Bs + (size_t)L * 16);
        }
        __syncthreads();  // drains vmcnt -> staged data visible
#pragma unroll
        for (int s = 0; s < 4; ++s) {
            int pos = ((s * 4 + q) ^ l16) * 16;
            short8 a0 = *(const short8*)((const char*)As + ((2 * wid + 0) * 16 + l16) * 256 + pos);
            short8 a1 = *(const short8*)((const char*)As + ((2 * wid + 1) * 16 + l16) * 256 + pos);
#pragma unroll
            for (int ct = 0; ct < 8; ++ct) {
                short8 b = *(const short8*)((const char*)Bs + (ct * 16 + l16) * 256 + pos);
                acc[0][ct] = __builtin_amdgcn_mfma_f32_16x16x32_bf16(a0, b, acc[0][ct], 0, 0, 0);
                acc[1][ct] = __builtin_amdgcn_mfma_f32_16x16x32_bf16(a1, b, acc[1][ct], 0, 0, 0);
            }
        }
    }
    // epilogue: C layout col = lane&15, row = q*4 + reg
#pragma unroll
    for (int rt = 0; rt < 2; ++rt) {
#pragma unroll
        for (int ct = 0; ct < 8; ++ct) {
            int h = ct * 16 + l16;
            float bv = bias[h];
#pragma unroll
            for (int reg = 0; reg < 4; ++reg) {
                int node = nodeBase + (2 * wid + rt) * 16 + q * 4 + reg;
                if (node < N) {
                    float v = acc[rt][ct][reg] + bv;
                    if (FINAL) {
                        outF[(size_t)node * FDIM + h] = v;
                    } else {
                        v = fmaxf(v, 0.f);
                        MxOut[(size_t)node * KDIM + 1024 + h] = f2bf(v);
                    }
                }
            }
        }
    }
}

__global__ void copy_emb(const float* __restrict__ e, float* __restrict__ out, int n) {
    int i = blockIdx.x * 256 + threadIdx.x;
    if (i < n) out[i] = e[i];
}

// ---------------- launch ----------------

extern "C" void kernel_launch(void* const* d_in, const int* in_sizes, int n_in,
                              void* d_out, int out_size, void* d_ws, size_t ws_size,
                              hipStream_t stream) {
    const float* x        = (const float*)d_in[0];
    const int* edge_index = (const int*)d_in[1];
    const int* edge_type  = (const int*)d_in[2];
    const float* rel_w0   = (const float*)d_in[3];
    const float* root_w0  = (const float*)d_in[4];
    const float* bias0    = (const float*)d_in[5];
    const float* rel_w1   = (const float*)d_in[6];
    const float* root_w1  = (const float*)d_in[7];
    const float* bias1    = (const float*)d_in[8];
    const float* rel_emb  = (const float*)d_in[9];

    int N = in_sizes[0] / FDIM;   // 50000
    int E = in_sizes[1] / 2;      // 800000
    int NSEG = N * RNUM;          // 400000
    const int* src = edge_index;
    const int* dst = edge_index + E;

    int nb_gemm = (N + 127) / 128;      // 391
    int NPAD = nb_gemm * 128;           // 50048 (staging reads padded rows)

    char* w = (char*)d_ws;
    auto alloc = [&](size_t bytes) -> char* {
        char* p = w;
        w += (bytes + 255) & ~(size_t)255;
        return p;
    };
    int* cnt     = (int*)alloc((size_t)NSEG * 4);        // reused as cursor
    int* row_ptr = (int*)alloc((size_t)(NSEG + 1) * 4);
    int* bsum    = (int*)alloc(1024 * 4);
    int* ssrc    = (int*)alloc((size_t)E * 4);
    ushort_t* Wt = (ushort_t*)alloc((size_t)2 * 9 * 16384 * 2);
    ushort_t* Mx = (ushort_t*)alloc((size_t)NPAD * KDIM * 2);   // ~115 MB
    int* cursor = cnt;
    (void)ws_size; (void)n_in; (void)out_size;

    int nb_seg  = (NSEG + 255) / 256;
    int nb_E    = (E + 255) / 256;
    int nb_scan = (NSEG + 1023) / 1024;
    int nb_mean = (NSEG * 16) / 256;        // 25000
    int nb_cast = (N * FDIM) / (256 * 8);   // 3125

    zero_kernel<<<nb_seg, 256, 0, stream>>>(cnt, NSEG);
    hist_kernel<<<nb_E, 256, 0, stream>>>(dst, edge_type, cnt, E);
    scan_a<<<nb_scan, 256, 0, stream>>>(cnt, row_ptr, bsum, NSEG);
    scan_b<<<1, 512, 0, stream>>>(bsum, nb_scan);
    scan_c<<<nb_seg, 256, 0, stream>>>(row_ptr, cursor, bsum, NSEG, E);
    scatter_kernel<<<nb_E, 256, 0, stream>>>(src, dst, edge_type, cursor, ssrc, E);
    transpose_w<<<9, 256, 0, stream>>>(rel_w0, root_w0, Wt);
    transpose_w<<<9, 256, 0, stream>>>(rel_w1, root_w1, Wt + 9 * 16384);
    cast_x<<<nb_cast, 256, 0, stream>>>(x, Mx, N * FDIM);

    seg_mean<<<nb_mean, 256, 0, stream>>>(row_ptr, ssrc, Mx, NSEG);
    rgcn_gemm<false><<<nb_gemm, 256, 0, stream>>>(Mx, Wt, bias0, nullptr, Mx, N);
    seg_mean<<<nb_mean, 256, 0, stream>>>(row_ptr, ssrc, Mx, NSEG);
    rgcn_gemm<true><<<nb_gemm, 256, 0, stream>>>(Mx, Wt + 9 * 16384, bias1,
                                                 (float*)d_out, nullptr, N);
    copy_emb<<<4, 256, 0, stream>>>(rel_emb, (float*)d_out + (size_t)N * FDIM,
                                    in_sizes[9]);
}

// Round 4
// 333.337 us; speedup vs baseline: 1.7162x; 1.0491x over previous
//
#include <hip/hip_runtime.h>

typedef unsigned short ushort_t;
typedef __attribute__((ext_vector_type(8))) short short8;
typedef __attribute__((ext_vector_type(4))) float f32x4;
typedef __attribute__((ext_vector_type(4))) int int4v;

#define RNUM 8
#define FDIM 128
#define KDIM 1152   // 9 * 128: slots 0..7 = per-relation means, slot 8 = x / relu(h)

__device__ __forceinline__ float bf2f(ushort_t u) {
    union { unsigned int i; float f; } x;
    x.i = ((unsigned int)u) << 16;
    return x.f;
}
__device__ __forceinline__ ushort_t f2bf(float f) {
    union { float f; unsigned int i; } x;
    x.f = f;
    unsigned int u = x.i;
    u += 0x7fffu + ((u >> 16) & 1u);   // round-to-nearest-even
    return (ushort_t)(u >> 16);
}

// async global->LDS, 16B per lane; LDS side must be wave-contiguous
__device__ __forceinline__ void gl_lds16(const void* g, void* s) {
    __builtin_amdgcn_global_load_lds(
        (const __attribute__((address_space(1))) unsigned int*)g,
        (__attribute__((address_space(3))) unsigned int*)s, 16, 0, 0);
}

// ---------------- linked-list segment index ----------------
// head[seg] -> most recent edge id, next[i] -> previous edge with same seg.
// Replaces hist+scan+scatter: no random 4B scatter into a big array
// (53 MB write-amplification in round 3); head is 1.6 MB L2-resident.

__global__ void init_head(int* __restrict__ head, int n) {
    int i = blockIdx.x * 256 + threadIdx.x;
    if (i < n) head[i] = -1;
}

__global__ void link_kernel(const int* __restrict__ dst, const int* __restrict__ et,
                            int* head, int* __restrict__ nxt, int E) {
    int i = blockIdx.x * 256 + threadIdx.x;
    if (i < E) {
        int seg = dst[i] * RNUM + et[i];
        nxt[i] = atomicExch(&head[seg], i);
    }
}

// ------- weight transpose + bf16 cast: Wt[r][h][f] = bf16(W[r][f][h]), r=8 -> root -------

__global__ __launch_bounds__(256) void transpose_w(const float* __restrict__ rel_w,
                                                   const float* __restrict__ root_w,
                                                   ushort_t* __restrict__ Wt) {
    int r = blockIdx.x;  // 0..8
    const float* src = (r < 8) ? (rel_w + r * 16384) : root_w;
    __shared__ ushort_t t[128 * 130];
    for (int idx = threadIdx.x; idx < 16384; idx += 256)
        t[(idx >> 7) * 130 + (idx & 127)] = f2bf(src[idx]);
    __syncthreads();
    ushort_t* d = Wt + r * 16384;
    for (int idx = threadIdx.x; idx < 16384; idx += 256)
        d[idx] = t[(idx & 127) * 130 + (idx >> 7)];
}

// ---------------- cast x (f32) into Mx slot 8 ----------------

__global__ void cast_x(const float* __restrict__ x, ushort_t* __restrict__ Mx, int total) {
    int i = (blockIdx.x * 256 + threadIdx.x) * 8;
    if (i >= total) return;
    float4 v0 = *(const float4*)(x + i);
    float4 v1 = *(const float4*)(x + i + 4);
    ushort_t o[8] = {f2bf(v0.x), f2bf(v0.y), f2bf(v0.z), f2bf(v0.w),
                     f2bf(v1.x), f2bf(v1.y), f2bf(v1.z), f2bf(v1.w)};
    int row = i >> 7, col = i & 127;
    *(int4v*)(Mx + (size_t)row * KDIM + 1024 + col) = *(int4v*)o;
}

// ---------------- phase A: per-(node,rel) segment means ----------------
// one quarter-wave (16 lanes x 16B) per segment; enumerate edges via the
// linked list (chains avg length E/NSEG = 2), gather rows from Mx slot 8,
// write mean into Mx slot (seg&7). Zero LDS -> max occupancy.

__global__ __launch_bounds__(256) void seg_mean(const int* __restrict__ head,
                                                const int* __restrict__ nxt,
                                                const int* __restrict__ esrc,
                                                ushort_t* Mx, int NSEG) {
    int t = blockIdx.x * 256 + threadIdx.x;
    int seg = t >> 4;
    int l16 = t & 15;
    if (seg >= NSEG) return;
    float acc[8];
#pragma unroll
    for (int k = 0; k < 8; ++k) acc[k] = 0.f;
    const ushort_t* gbase = Mx + 1024 + (size_t)l16 * 8;
    int cnt = 0;
    int j = head[seg];
    while (j >= 0) {
        int s = esrc[j];       // independent loads: s and jn issue together,
        int jn = nxt[j];       // row gather depends only on s
        int4v v = *(const int4v*)(gbase + (size_t)s * KDIM);
        ushort_t* p = (ushort_t*)&v;
#pragma unroll
        for (int k = 0; k < 8; ++k) acc[k] += bf2f(p[k]);
        ++cnt;
        j = jn;
    }
    float sc = (cnt > 0) ? 1.0f / (float)cnt : 0.f;
    ushort_t ov[8];
#pragma unroll
    for (int k = 0; k < 8; ++k) ov[k] = f2bf(acc[k] * sc);
    *(int4v*)(Mx + (size_t)(seg >> 3) * KDIM + (seg & 7) * 128 + l16 * 8) = *(int4v*)ov;
}

// ---------------- phase B: dense GEMM  C[128n x 128h] = Mx[128n x 1152k] @ Wt^T ----------
// A,B staged per r-slot via global_load_lds (16B) into XOR-swizzled contiguous LDS.
// LDS chunk layout: 16B chunk c of row n stored at position c ^ (n & 15).

template <bool FINAL>
__global__ __launch_bounds__(256) void rgcn_gemm(
    const ushort_t* Mx, const ushort_t* __restrict__ Wt,
    const float* __restrict__ bias, float* __restrict__ outF,
    ushort_t* MxOut, int N) {
    __shared__ ushort_t As[128 * 128];
    __shared__ ushort_t Bs[128 * 128];
    int tid = threadIdx.x;
    int wid = tid >> 6, lane = tid & 63;
    int l16 = lane & 15, q = lane >> 4;
    int nodeBase = blockIdx.x * 128;

    f32x4 acc[2][8];
#pragma unroll
    for (int rt = 0; rt < 2; ++rt)
#pragma unroll
        for (int ct = 0; ct < 8; ++ct) acc[rt][ct] = (f32x4){0.f, 0.f, 0.f, 0.f};

    for (int r = 0; r < 9; ++r) {
        __syncthreads();  // previous iteration's LDS reads done
#pragma unroll
        for (int i = 0; i < 8; ++i) {
            int L = i * 256 + tid;          // 16B slot index, wave-contiguous
            int row = L >> 4;               // 0..127
            int c = (L & 15) ^ (row & 15);  // logical chunk for this slot
            gl_lds16(Mx + (size_t)(nodeBase + row) * KDIM + r * 128 + c * 8,
                     (char*)As + (size_t)L * 16);
            gl_lds16(Wt + r * 16384 + row * 128 + c * 8,
                     (char*)Bs + (size_t)L * 16);
        }
        __syncthreads();  // drains vmcnt -> staged data visible
#pragma unroll
        for (int s = 0; s < 4; ++s) {
            int pos = ((s * 4 + q) ^ l16) * 16;
            short8 a0 = *(const short8*)((const char*)As + ((2 * wid + 0) * 16 + l16) * 256 + pos);
            short8 a1 = *(const short8*)((const char*)As + ((2 * wid + 1) * 16 + l16) * 256 + pos);
#pragma unroll
            for (int ct = 0; ct < 8; ++ct) {
                short8 b = *(const short8*)((const char*)Bs + (ct * 16 + l16) * 256 + pos);
                acc[0][ct] = __builtin_amdgcn_mfma_f32_16x16x32_bf16(a0, b, acc[0][ct], 0, 0, 0);
                acc[1][ct] = __builtin_amdgcn_mfma_f32_16x16x32_bf16(a1, b, acc[1][ct], 0, 0, 0);
            }
        }
    }
    // epilogue: C layout col = lane&15, row = q*4 + reg
#pragma unroll
    for (int rt = 0; rt < 2; ++rt) {
#pragma unroll
        for (int ct = 0; ct < 8; ++ct) {
            int h = ct * 16 + l16;
            float bv = bias[h];
#pragma unroll
            for (int reg = 0; reg < 4; ++reg) {
                int node = nodeBase + (2 * wid + rt) * 16 + q * 4 + reg;
                if (node < N) {
                    float v = acc[rt][ct][reg] + bv;
                    if (FINAL) {
                        outF[(size_t)node * FDIM + h] = v;
                    } else {
                        v = fmaxf(v, 0.f);
                        MxOut[(size_t)node * KDIM + 1024 + h] = f2bf(v);
                    }
                }
            }
        }
    }
}

__global__ void copy_emb(const float* __restrict__ e, float* __restrict__ out, int n) {
    int i = blockIdx.x * 256 + threadIdx.x;
    if (i < n) out[i] = e[i];
}

// ---------------- launch ----------------

extern "C" void kernel_launch(void* const* d_in, const int* in_sizes, int n_in,
                              void* d_out, int out_size, void* d_ws, size_t ws_size,
                              hipStream_t stream) {
    const float* x        = (const float*)d_in[0];
    const int* edge_index = (const int*)d_in[1];
    const int* edge_type  = (const int*)d_in[2];
    const float* rel_w0   = (const float*)d_in[3];
    const float* root_w0  = (const float*)d_in[4];
    const float* bias0    = (const float*)d_in[5];
    const float* rel_w1   = (const float*)d_in[6];
    const float* root_w1  = (const float*)d_in[7];
    const float* bias1    = (const float*)d_in[8];
    const float* rel_emb  = (const float*)d_in[9];

    int N = in_sizes[0] / FDIM;   // 50000
    int E = in_sizes[1] / 2;      // 800000
    int NSEG = N * RNUM;          // 400000
    const int* src = edge_index;
    const int* dst = edge_index + E;

    int nb_gemm = (N + 127) / 128;      // 391
    int NPAD = nb_gemm * 128;           // 50048 (staging reads padded rows)

    char* w = (char*)d_ws;
    auto alloc = [&](size_t bytes) -> char* {
        char* p = w;
        w += (bytes + 255) & ~(size_t)255;
        return p;
    };
    int* head    = (int*)alloc((size_t)NSEG * 4);
    int* nxt     = (int*)alloc((size_t)E * 4);
    ushort_t* Wt = (ushort_t*)alloc((size_t)2 * 9 * 16384 * 2);
    ushort_t* Mx = (ushort_t*)alloc((size_t)NPAD * KDIM * 2);   // ~115 MB
    (void)ws_size; (void)n_in; (void)out_size;

    int nb_seg  = (NSEG + 255) / 256;
    int nb_E    = (E + 255) / 256;
    int nb_mean = (NSEG * 16) / 256;        // 25000
    int nb_cast = (N * FDIM) / (256 * 8);   // 3125

    init_head<<<nb_seg, 256, 0, stream>>>(head, NSEG);
    link_kernel<<<nb_E, 256, 0, stream>>>(dst, edge_type, head, nxt, E);
    transpose_w<<<9, 256, 0, stream>>>(rel_w0, root_w0, Wt);
    transpose_w<<<9, 256, 0, stream>>>(rel_w1, root_w1, Wt + 9 * 16384);
    cast_x<<<nb_cast, 256, 0, stream>>>(x, Mx, N * FDIM);

    seg_mean<<<nb_mean, 256, 0, stream>>>(head, nxt, src, Mx, NSEG);
    rgcn_gemm<false><<<nb_gemm, 256, 0, stream>>>(Mx, Wt, bias0, nullptr, Mx, N);
    seg_mean<<<nb_mean, 256, 0, stream>>>(head, nxt, src, Mx, NSEG);
    rgcn_gemm<true><<<nb_gemm, 256, 0, stream>>>(Mx, Wt + 9 * 16384, bias1,
                                                 (float*)d_out, nullptr, N);
    copy_emb<<<4, 256, 0, stream>>>(rel_emb, (float*)d_out + (size_t)N * FDIM,
                                    in_sizes[9]);
}